// Round 1
// baseline (74.014 us; speedup 1.0000x reference)
//
#include <hip/hip_runtime.h>
#include <hip/hip_bf16.h>
#include <stdint.h>

typedef __bf16 bf16x8 __attribute__((ext_vector_type(8)));
typedef float f32x4 __attribute__((ext_vector_type(4)));

#define KDIM 256
#define BK 64
#define M_PAD 17536      // ceil(4*66*66 / 128) * 128
#define NPIX 16384       // 4*64*64

__device__ __forceinline__ float b2f(ushort u){
    union { float f; uint32_t i; } x; x.i = ((uint32_t)u) << 16; return x.f;
}
__device__ __forceinline__ ushort f2b(float f){
    uint32_t u = __float_as_uint(f);
    uint32_t r = (u + 0x7fffu + ((u >> 16) & 1u)) >> 16;
    return (ushort)r;
}

// ---------------- LayerNorm stats: one block per (b,c), 4096 elems ----------
__global__ void ln_stats(const float* __restrict__ x, float* __restrict__ mean,
                         float* __restrict__ rstd){
    int bc = blockIdx.x;
    const float4* p = (const float4*)(x + (size_t)bc * 4096);
    int tid = threadIdx.x;
    float s = 0.f, s2 = 0.f;
#pragma unroll
    for (int i = 0; i < 4; ++i){
        float4 v = p[i * 256 + tid];
        s  += v.x + v.y + v.z + v.w;
        s2 += v.x * v.x + v.y * v.y + v.z * v.z + v.w * v.w;
    }
#pragma unroll
    for (int off = 32; off; off >>= 1){
        s  += __shfl_xor(s, off);
        s2 += __shfl_xor(s2, off);
    }
    __shared__ float rs[8];
    int wid = tid >> 6;
    if ((tid & 63) == 0){ rs[wid] = s; rs[4 + wid] = s2; }
    __syncthreads();
    if (tid == 0){
        float S  = rs[0] + rs[1] + rs[2] + rs[3];
        float S2 = rs[4] + rs[5] + rs[6] + rs[7];
        float m  = S * (1.f / 4096.f);
        float v  = S2 * (1.f / 4096.f) - m * m;
        mean[bc] = m;
        rstd[bc] = rsqrtf(v + 1e-5f);
    }
}

// ------- apply LN + transpose to channels-last padded bf16 [B,66,66,C] ------
__global__ void ln_apply(const float* __restrict__ x, const float* __restrict__ mean,
                         const float* __restrict__ rstd, ushort* __restrict__ xn){
    int blk = blockIdx.x;            // b*64 + h
    int b = blk >> 6, h = blk & 63;
    int c = threadIdx.x;             // 256 channels
    int bc = b * 256 + c;
    float mu = mean[bc], rv = rstd[bc];
    const float* px = x + ((size_t)bc * 64 + h) * 64;
    ushort* po = xn + (((size_t)(b * 66 + h + 1) * 66) + 1) * 256 + c;
#pragma unroll 4
    for (int w = 0; w < 64; ++w)
        po[(size_t)w * 256] = f2b((px[w] - mu) * rv);
}

// ---- transpose+convert weights fp32 [K][N] -> bf16 [N][K], 4 matrices ------
__global__ void wt_cvt(const float* __restrict__ Wq, const float* __restrict__ Wk,
                       const float* __restrict__ Wv, const float* __restrict__ Wo,
                       ushort* __restrict__ wt){
    int n = blockIdx.x, k = threadIdx.x;
    int src = k * 256 + n, dst = n * 256 + k;
    wt[dst]           = f2b(Wq[src]);
    wt[65536 + dst]   = f2b(Wk[src]);
    wt[131072 + dst]  = f2b(Wv[src]);
    wt[196608 + dst]  = f2b(Wo[src]);
}

// --------------------------- MFMA GEMM ---------------------------------
// Z[x][y] = dot(X[x][0:256], Y[y][0:256])  (both row-major, K contiguous)
// MODE 0: zb[x*256+y] = bf16((acc + bias[y]) * alpha)      (q/k/v linears)
// MODE 1: zf[((y>>12)*256 + x)*4096 + (y&4095)] = acc + bias[x]  (out, NCHW)
template<int MODE>
__global__ __launch_bounds__(256, 2)
void gemm_nt(const ushort* __restrict__ X, const ushort* __restrict__ Y,
             const float* __restrict__ bias, float alpha,
             ushort* __restrict__ zb, float* __restrict__ zf){
    __shared__ ushort ldsX[2][128 * 64];
    __shared__ ushort ldsY[2][128 * 64];
    const int tid  = threadIdx.x;
    const int lane = tid & 63;
    const int wid  = tid >> 6;
    const int wm   = wid >> 1, wn = wid & 1;
    const int x0   = blockIdx.x * 128, y0 = blockIdx.y * 128;

    // stage one [128 rows][64 K] tile for X and Y, XOR-swizzled at 16B-chunk
    // granularity: LDS dest stays linear (global_load_lds requirement), the
    // global SOURCE chunk is pre-swizzled; reads apply the same XOR.
    auto stage = [&](int buf, int k0){
#pragma unroll
        for (int i = 0; i < 4; ++i){
            int f   = i * 256 + tid;          // dest 16B-chunk index
            int row = f >> 3, cp = f & 7;
            int cs  = cp ^ (row & 7);         // source chunk (involution)
            const ushort* gx = X + (size_t)(x0 + row) * KDIM + k0 + cs * 8;
            const ushort* gy = Y + (size_t)(y0 + row) * KDIM + k0 + cs * 8;
            __builtin_amdgcn_global_load_lds(
                (const __attribute__((address_space(1))) void*)gx,
                (__attribute__((address_space(3))) void*)&ldsX[buf][f * 8], 16, 0, 0);
            __builtin_amdgcn_global_load_lds(
                (const __attribute__((address_space(1))) void*)gy,
                (__attribute__((address_space(3))) void*)&ldsY[buf][f * 8], 16, 0, 0);
        }
    };

    f32x4 acc[4][4];
#pragma unroll
    for (int i = 0; i < 4; ++i)
#pragma unroll
        for (int j = 0; j < 4; ++j) acc[i][j] = f32x4{0.f, 0.f, 0.f, 0.f};

    stage(0, 0);
    int buf = 0;
    for (int t = 0; t < 4; ++t){            // K = 256 = 4 * BK
        __syncthreads();                     // drains vmcnt for prior stage
        if (t < 3) stage(buf ^ 1, (t + 1) * BK);
#pragma unroll
        for (int kk = 0; kk < 2; ++kk){      // two K=32 MFMA steps per BK=64
            bf16x8 xa[4], yb[4];
#pragma unroll
            for (int fm = 0; fm < 4; ++fm){
                int r = wm * 64 + fm * 16 + (lane & 15);
                int c = kk * 4 + (lane >> 4);
                xa[fm] = *(const bf16x8*)&ldsX[buf][(r * 8 + (c ^ (r & 7))) * 8];
            }
#pragma unroll
            for (int fn = 0; fn < 4; ++fn){
                int r = wn * 64 + fn * 16 + (lane & 15);
                int c = kk * 4 + (lane >> 4);
                yb[fn] = *(const bf16x8*)&ldsY[buf][(r * 8 + (c ^ (r & 7))) * 8];
            }
#pragma unroll
            for (int fm = 0; fm < 4; ++fm)
#pragma unroll
                for (int fn = 0; fn < 4; ++fn)
                    acc[fm][fn] = __builtin_amdgcn_mfma_f32_16x16x32_bf16(
                        xa[fm], yb[fn], acc[fm][fn], 0, 0, 0);
        }
        buf ^= 1;
    }

    // epilogue: C/D frag mapping col = lane&15 (Y-row), row = (lane>>4)*4+r (X-row)
#pragma unroll
    for (int fm = 0; fm < 4; ++fm){
#pragma unroll
        for (int fn = 0; fn < 4; ++fn){
            int xr = x0 + wm * 64 + fm * 16 + ((lane >> 4) << 2);
            int yc = y0 + wn * 64 + fn * 16 + (lane & 15);
            if (MODE == 0){
                float bv = bias[yc];
#pragma unroll
                for (int r = 0; r < 4; ++r)
                    zb[(size_t)(xr + r) * KDIM + yc] =
                        f2b((acc[fm][fn][r] + bv) * alpha);
            } else {
                int bpix = yc >> 12, hw = yc & 4095;
#pragma unroll
                for (int r = 0; r < 4; ++r){
                    int ch = xr + r;
                    zf[((size_t)(bpix * 256 + ch)) * 4096 + hw] =
                        acc[fm][fn][r] + bias[ch];
                }
            }
        }
    }
}

// ------------------- 3x3 window attention: one wave per pixel ---------------
__global__ __launch_bounds__(256)
void attn_win(const ushort* __restrict__ qf, const ushort* __restrict__ kf,
              const ushort* __restrict__ vf, ushort* __restrict__ ctx){
    int pix  = blockIdx.x * 4 + (threadIdx.x >> 6);
    int lane = threadIdx.x & 63;
    int b = pix >> 12, hw = pix & 4095;
    int h = hw >> 6, w = hw & 63;
    size_t base = (size_t)b * 66 * 66;
    size_t crow = base + (size_t)(h + 1) * 66 + (w + 1);

    ushort4 q4 = *(const ushort4*)(qf + crow * 256 + lane * 4);
    float q0 = b2f(q4.x), q1 = b2f(q4.y), q2 = b2f(q4.z), q3 = b2f(q4.w);

    float lg[9];
    size_t rows[9];
#pragma unroll
    for (int n = 0; n < 9; ++n){
        int dh = n / 3, dw = n % 3;
        size_t row = base + (size_t)(h + dh) * 66 + (w + dw);
        rows[n] = row;
        ushort4 k4 = *(const ushort4*)(kf + row * 256 + lane * 4);
        float d = q0 * b2f(k4.x) + q1 * b2f(k4.y) + q2 * b2f(k4.z) + q3 * b2f(k4.w);
#pragma unroll
        for (int off = 32; off; off >>= 1) d += __shfl_xor(d, off);
        lg[n] = d;
    }
    float m = lg[0];
#pragma unroll
    for (int n = 1; n < 9; ++n) m = fmaxf(m, lg[n]);
    float e[9], s = 0.f;
#pragma unroll
    for (int n = 0; n < 9; ++n){ e[n] = __expf(lg[n] - m); s += e[n]; }
    float inv = 1.f / s;

    float c0 = 0.f, c1 = 0.f, c2 = 0.f, c3 = 0.f;
#pragma unroll
    for (int n = 0; n < 9; ++n){
        float a = e[n] * inv;
        ushort4 v4 = *(const ushort4*)(vf + rows[n] * 256 + lane * 4);
        c0 += a * b2f(v4.x); c1 += a * b2f(v4.y);
        c2 += a * b2f(v4.z); c3 += a * b2f(v4.w);
    }
    ushort4 o; o.x = f2b(c0); o.y = f2b(c1); o.z = f2b(c2); o.w = f2b(c3);
    *(ushort4*)(ctx + (size_t)pix * 256 + lane * 4) = o;
}

// ---------------------------------------------------------------------------
extern "C" void kernel_launch(void* const* d_in, const int* in_sizes, int n_in,
                              void* d_out, int out_size, void* d_ws, size_t ws_size,
                              hipStream_t stream){
    const float* x  = (const float*)d_in[0];
    const float* Wq = (const float*)d_in[1];
    const float* bq = (const float*)d_in[2];
    const float* Wk = (const float*)d_in[3];
    const float* bk = (const float*)d_in[4];
    const float* Wv = (const float*)d_in[5];
    const float* bv = (const float*)d_in[6];
    const float* Wo = (const float*)d_in[7];
    const float* bo = (const float*)d_in[8];
    float* out = (float*)d_out;

    char* ws = (char*)d_ws;
    ushort* wt   = (ushort*)(ws);                    // 4 * 65536 bf16 (Wq,Wk,Wv,Wo transposed)
    float*  mean = (float*) (ws + 524288);           // 1024
    float*  rstd = (float*) (ws + 528384);           // 1024
    ushort* xn   = (ushort*)(ws + 532480);           // [M_PAD][256] bf16 (LN'd, padded, CL)
    ushort* qf   = (ushort*)(ws + 9510912);          // [M_PAD][256]
    ushort* kf   = (ushort*)(ws + 18489344);         // [M_PAD][256]
    ushort* vf   = (ushort*)(ws + 27467776);         // [M_PAD][256]
    ushort* ctx  = (ushort*)(ws + 36446208);         // [NPIX][256]

    // zero xn: provides the spatial zero-padding ring + padded tail rows
    hipMemsetAsync(xn, 0, (size_t)M_PAD * 256 * 2, stream);

    wt_cvt<<<256, 256, 0, stream>>>(Wq, Wk, Wv, Wo, wt);
    ln_stats<<<1024, 256, 0, stream>>>(x, mean, rstd);
    ln_apply<<<256, 256, 0, stream>>>(x, mean, rstd, xn);

    dim3 g1(137, 2);   // M_PAD/128 x 256/128
    gemm_nt<0><<<g1, 256, 0, stream>>>(xn, wt,           bq, 0.0625f, qf, nullptr);
    gemm_nt<0><<<g1, 256, 0, stream>>>(xn, wt + 65536,   bk, 1.0f,    kf, nullptr);
    gemm_nt<0><<<g1, 256, 0, stream>>>(xn, wt + 131072,  bv, 1.0f,    vf, nullptr);

    attn_win<<<4096, 256, 0, stream>>>(qf, kf, vf, ctx);

    dim3 g2(2, 128);   // 256/128 x NPIX/128
    gemm_nt<1><<<g2, 256, 0, stream>>>(wt + 196608, ctx, bo, 1.0f, nullptr, out);
}

// Round 2
// 58.093 us; speedup vs baseline: 1.2741x; 1.2741x over previous
//
#include <hip/hip_runtime.h>
#include <hip/hip_bf16.h>
#include <stdint.h>

typedef __bf16 bf16x8 __attribute__((ext_vector_type(8)));
typedef float f32x4 __attribute__((ext_vector_type(4)));

#define KDIM 256
#define M_PAD 17536      // ceil(4*66*66 / 128) * 128
#define NPIX 16384       // 4*64*64
#define QKVS 768         // fused q/k/v row stride

__device__ __forceinline__ float b2f(ushort u){
    union { float f; uint32_t i; } x; x.i = ((uint32_t)u) << 16; return x.f;
}
__device__ __forceinline__ ushort f2b(float f){
    uint32_t u = __float_as_uint(f);
    uint32_t r = (u + 0x7fffu + ((u >> 16) & 1u)) >> 16;
    return (ushort)r;
}

// ------------------- fused prep kernel (block-range dispatch) ---------------
// blocks [0,1024):       ln_stats, one block per (b,c)
// blocks [1024,1280):    weight transpose fp32[K][N] -> bf16[N][K] via LDS
// block  1280:           bias concat (bq*s, bk, bv)
// blocks [1281,1281+144): zero the 1152 pad/tail rows of xn
__global__ __launch_bounds__(256)
void prep(const float* __restrict__ x,
          const float* __restrict__ Wq, const float* __restrict__ bq,
          const float* __restrict__ Wk, const float* __restrict__ bk,
          const float* __restrict__ Wv, const float* __restrict__ bv,
          const float* __restrict__ Wo,
          ushort* __restrict__ wt, float* __restrict__ bias_all,
          float* __restrict__ mean, float* __restrict__ rstd,
          ushort* __restrict__ xn){
    __shared__ float sh[32 * 33];
    const int bid = blockIdx.x, tid = threadIdx.x;

    if (bid < 1024){                       // ---- LN stats ----
        int bc = bid;
        const float4* p = (const float4*)(x + (size_t)bc * 4096);
        float s = 0.f, s2 = 0.f;
#pragma unroll
        for (int i = 0; i < 4; ++i){
            float4 v = p[i * 256 + tid];
            s  += v.x + v.y + v.z + v.w;
            s2 += v.x * v.x + v.y * v.y + v.z * v.z + v.w * v.w;
        }
#pragma unroll
        for (int off = 32; off; off >>= 1){
            s  += __shfl_xor(s, off);
            s2 += __shfl_xor(s2, off);
        }
        int wid = tid >> 6;
        if ((tid & 63) == 0){ sh[wid] = s; sh[4 + wid] = s2; }
        __syncthreads();
        if (tid == 0){
            float S  = sh[0] + sh[1] + sh[2] + sh[3];
            float S2 = sh[4] + sh[5] + sh[6] + sh[7];
            float m  = S * (1.f / 4096.f);
            float v  = S2 * (1.f / 4096.f) - m * m;
            mean[bc] = m;
            rstd[bc] = rsqrtf(v + 1e-5f);
        }
    } else if (bid < 1280){                // ---- weight transpose ----
        int t = bid - 1024;
        int m = t >> 6, tile = t & 63;
        int ti = tile & 7, tj = tile >> 3;        // ti: dst row block, tj: src row block
        const float* src = (m == 0) ? Wq : (m == 1) ? Wk : (m == 2) ? Wv : Wo;
        float scale = (m == 0) ? 0.0625f : 1.0f;  // fold C^-0.5 into Wq
        int roff = m * 256;                       // dst row offset in wt
        int tx = tid & 31, ty = tid >> 5;
#pragma unroll
        for (int i = 0; i < 4; ++i){
            int sr = tj * 32 + ty + i * 8;
            sh[(ty + i * 8) * 33 + tx] = src[sr * 256 + ti * 32 + tx] * scale;
        }
        __syncthreads();
#pragma unroll
        for (int i = 0; i < 4; ++i){
            int dr = ti * 32 + ty + i * 8;
            wt[(size_t)(roff + dr) * 256 + tj * 32 + tx] =
                f2b(sh[tx * 33 + ty + i * 8]);
        }
    } else if (bid == 1280){               // ---- bias concat ----
        bias_all[tid]       = bq[tid] * 0.0625f;
        bias_all[256 + tid] = bk[tid];
        bias_all[512 + tid] = bv[tid];
    } else {                               // ---- zero pad/tail rows of xn ----
        int p = (bid - 1281) * 8 + (tid >> 5);   // pad-row index [0,1152)
        int row;
        if (p < 1040){
            int b = p / 260, i = p % 260;
            int h, w;
            if (i < 66)       { h = 0;       w = i; }
            else if (i < 132) { h = 65;      w = i - 66; }
            else if (i < 196) { h = i - 131; w = 0; }     // h = 1..64
            else              { h = i - 195; w = 65; }
            row = b * 4356 + h * 66 + w;
        } else {
            row = 17424 + (p - 1040);
        }
        uint4 z = {0, 0, 0, 0};
        *(uint4*)(xn + (size_t)row * 256 + (tid & 31) * 8) = z;
    }
}

// ------- apply LN + transpose to channels-last padded bf16 [B,66,66,C] ------
__global__ void ln_apply(const float* __restrict__ x, const float* __restrict__ mean,
                         const float* __restrict__ rstd, ushort* __restrict__ xn){
    int blk = blockIdx.x;            // b*64 + h
    int b = blk >> 6, h = blk & 63;
    int c = threadIdx.x;             // 256 channels
    int bc = b * 256 + c;
    float mu = mean[bc], rv = rstd[bc];
    const float* px = x + ((size_t)bc * 64 + h) * 64;
    ushort* po = xn + (((size_t)(b * 66 + h + 1) * 66) + 1) * 256 + c;
#pragma unroll 4
    for (int w = 0; w < 64; ++w)
        po[(size_t)w * 256] = f2b((px[w] - mu) * rv);
}

// --------------------------- MFMA GEMM ---------------------------------
// Z[x][y] = dot(X[x][0:256], Y[y][0:256])  (both row-major, K contiguous)
// MODE 0: zb[x*NOUT+y] = bf16(acc + bias[y])                (fused qkv linears)
// MODE 1: zf[((y>>12)*256 + x)*4096 + (y&4095)] = acc + bias[x]  (out, NCHW)
template<int MODE, int NOUT>
__global__ __launch_bounds__(256, 2)
void gemm_nt(const ushort* __restrict__ X, const ushort* __restrict__ Y,
             const float* __restrict__ bias,
             ushort* __restrict__ zb, float* __restrict__ zf){
    __shared__ ushort ldsX[2][128 * 64];
    __shared__ ushort ldsY[2][128 * 64];
    const int tid  = threadIdx.x;
    const int lane = tid & 63;
    const int wid  = tid >> 6;
    const int wm   = wid >> 1, wn = wid & 1;
    const int x0   = blockIdx.x * 128, y0 = blockIdx.y * 128;

    // stage one [128 rows][64 K] tile for X and Y, XOR-swizzled at 16B-chunk
    // granularity: LDS dest stays linear (global_load_lds requirement), the
    // global SOURCE chunk is pre-swizzled; reads apply the same XOR.
    auto stage = [&](int buf, int k0){
#pragma unroll
        for (int i = 0; i < 4; ++i){
            int f   = i * 256 + tid;          // dest 16B-chunk index
            int row = f >> 3, cp = f & 7;
            int cs  = cp ^ (row & 7);         // source chunk (involution)
            const ushort* gx = X + (size_t)(x0 + row) * KDIM + k0 + cs * 8;
            const ushort* gy = Y + (size_t)(y0 + row) * KDIM + k0 + cs * 8;
            __builtin_amdgcn_global_load_lds(
                (const __attribute__((address_space(1))) void*)gx,
                (__attribute__((address_space(3))) void*)&ldsX[buf][f * 8], 16, 0, 0);
            __builtin_amdgcn_global_load_lds(
                (const __attribute__((address_space(1))) void*)gy,
                (__attribute__((address_space(3))) void*)&ldsY[buf][f * 8], 16, 0, 0);
        }
    };

    f32x4 acc[4][4];
#pragma unroll
    for (int i = 0; i < 4; ++i)
#pragma unroll
        for (int j = 0; j < 4; ++j) acc[i][j] = f32x4{0.f, 0.f, 0.f, 0.f};

    stage(0, 0);
    int buf = 0;
    for (int t = 0; t < 4; ++t){            // K = 256 = 4 * 64
        __syncthreads();                     // drains vmcnt for prior stage
        if (t < 3) stage(buf ^ 1, (t + 1) * 64);
#pragma unroll
        for (int kk = 0; kk < 2; ++kk){      // two K=32 MFMA steps per BK=64
            bf16x8 xa[4], yb[4];
#pragma unroll
            for (int fm = 0; fm < 4; ++fm){
                int r = wm * 64 + fm * 16 + (lane & 15);
                int c = kk * 4 + (lane >> 4);
                xa[fm] = *(const bf16x8*)&ldsX[buf][(r * 8 + (c ^ (r & 7))) * 8];
            }
#pragma unroll
            for (int fn = 0; fn < 4; ++fn){
                int r = wn * 64 + fn * 16 + (lane & 15);
                int c = kk * 4 + (lane >> 4);
                yb[fn] = *(const bf16x8*)&ldsY[buf][(r * 8 + (c ^ (r & 7))) * 8];
            }
#pragma unroll
            for (int fm = 0; fm < 4; ++fm)
#pragma unroll
                for (int fn = 0; fn < 4; ++fn)
                    acc[fm][fn] = __builtin_amdgcn_mfma_f32_16x16x32_bf16(
                        xa[fm], yb[fn], acc[fm][fn], 0, 0, 0);
        }
        buf ^= 1;
    }

    // epilogue: C/D frag mapping col = lane&15 (Y-row), row = (lane>>4)*4+r (X-row)
#pragma unroll
    for (int fm = 0; fm < 4; ++fm){
#pragma unroll
        for (int fn = 0; fn < 4; ++fn){
            int xr = x0 + wm * 64 + fm * 16 + ((lane >> 4) << 2);
            int yc = y0 + wn * 64 + fn * 16 + (lane & 15);
            if (MODE == 0){
                float bv = bias[yc];
#pragma unroll
                for (int r = 0; r < 4; ++r)
                    zb[(size_t)(xr + r) * NOUT + yc] = f2b(acc[fm][fn][r] + bv);
            } else {
                int bpix = yc >> 12, hw = yc & 4095;
#pragma unroll
                for (int r = 0; r < 4; ++r){
                    int ch = xr + r;
                    zf[((size_t)(bpix * 256 + ch)) * 4096 + hw] =
                        acc[fm][fn][r] + bias[ch];
                }
            }
        }
    }
}

// ------------------- 3x3 window attention: one wave per pixel ---------------
__global__ __launch_bounds__(256)
void attn_win(const ushort* __restrict__ qkv, ushort* __restrict__ ctx){
    int pix  = blockIdx.x * 4 + (threadIdx.x >> 6);
    int lane = threadIdx.x & 63;
    int b = pix >> 12, hw = pix & 4095;
    int h = hw >> 6, w = hw & 63;
    size_t base = (size_t)b * 66 * 66;
    size_t crow = base + (size_t)(h + 1) * 66 + (w + 1);

    ushort4 q4 = *(const ushort4*)(qkv + crow * QKVS + lane * 4);
    float q0 = b2f(q4.x), q1 = b2f(q4.y), q2 = b2f(q4.z), q3 = b2f(q4.w);

    float lg[9];
    size_t rows[9];
#pragma unroll
    for (int n = 0; n < 9; ++n){
        int dh = n / 3, dw = n % 3;
        size_t row = base + (size_t)(h + dh) * 66 + (w + dw);
        rows[n] = row;
        ushort4 k4 = *(const ushort4*)(qkv + row * QKVS + 256 + lane * 4);
        float d = q0 * b2f(k4.x) + q1 * b2f(k4.y) + q2 * b2f(k4.z) + q3 * b2f(k4.w);
#pragma unroll
        for (int off = 32; off; off >>= 1) d += __shfl_xor(d, off);
        lg[n] = d;
    }
    float m = lg[0];
#pragma unroll
    for (int n = 1; n < 9; ++n) m = fmaxf(m, lg[n]);
    float e[9], s = 0.f;
#pragma unroll
    for (int n = 0; n < 9; ++n){ e[n] = __expf(lg[n] - m); s += e[n]; }
    float inv = 1.f / s;

    float c0 = 0.f, c1 = 0.f, c2 = 0.f, c3 = 0.f;
#pragma unroll
    for (int n = 0; n < 9; ++n){
        float a = e[n] * inv;
        ushort4 v4 = *(const ushort4*)(qkv + rows[n] * QKVS + 512 + lane * 4);
        c0 += a * b2f(v4.x); c1 += a * b2f(v4.y);
        c2 += a * b2f(v4.z); c3 += a * b2f(v4.w);
    }
    ushort4 o; o.x = f2b(c0); o.y = f2b(c1); o.z = f2b(c2); o.w = f2b(c3);
    *(ushort4*)(ctx + (size_t)pix * 256 + lane * 4) = o;
}

// ---------------------------------------------------------------------------
extern "C" void kernel_launch(void* const* d_in, const int* in_sizes, int n_in,
                              void* d_out, int out_size, void* d_ws, size_t ws_size,
                              hipStream_t stream){
    const float* x  = (const float*)d_in[0];
    const float* Wq = (const float*)d_in[1];
    const float* bq = (const float*)d_in[2];
    const float* Wk = (const float*)d_in[3];
    const float* bk = (const float*)d_in[4];
    const float* Wv = (const float*)d_in[5];
    const float* bv = (const float*)d_in[6];
    const float* Wo = (const float*)d_in[7];
    const float* bo = (const float*)d_in[8];
    float* out = (float*)d_out;

    char* ws = (char*)d_ws;
    ushort* wt       = (ushort*)(ws);              // [1024][256] bf16: qkv(768) + WoT(256)
    float*  bias_all = (float*) (ws + 524288);     // 768 floats
    float*  mean     = (float*) (ws + 528384);     // 1024
    float*  rstd     = (float*) (ws + 532480);     // 1024
    ushort* xn       = (ushort*)(ws + 536576);     // [M_PAD][256] bf16
    ushort* qkv      = (ushort*)(ws + 9515008);    // [M_PAD][768] bf16
    ushort* ctx      = (ushort*)(ws + 36450304);   // [NPIX][256] bf16

    prep<<<1425, 256, 0, stream>>>(x, Wq, bq, Wk, bk, Wv, bv, Wo,
                                   wt, bias_all, mean, rstd, xn);
    ln_apply<<<256, 256, 0, stream>>>(x, mean, rstd, xn);

    dim3 g1(137, 6);   // M_PAD/128 x 768/128
    gemm_nt<0, QKVS><<<g1, 256, 0, stream>>>(xn, wt, bias_all, qkv, nullptr);

    attn_win<<<4096, 256, 0, stream>>>(qkv, ctx);

    dim3 g2(2, 128);   // 256/128 x NPIX/128
    gemm_nt<1, 0><<<g2, 256, 0, stream>>>(wt + 768 * 256, ctx, bo, nullptr, out);
}